// Round 8
// baseline (284.155 us; speedup 1.0000x reference)
//
#include <hip/hip_runtime.h>

// PillarFeatureNet scatter-sum:
//   out[c, p] = sum_{i : indices[i]==p} x[i, c]
// x: (2,000,000, 64) fp32, indices: (2,000,000) int32 in [0, 262144)
// out: (64, 262144) fp32
//
// Round 8: gather restructured for memory-level parallelism. R7 decomposition
// (284us total, non-gather phases modeled ~40us) says gather ~220us vs its
// ~95us traffic floor -> latency-bound: per-iteration sorted->x dependent
// chain + serial short-loop tails. Fix: prefetch segment ids lane-distributed
// (1 coalesced load/pillar, latency overlapped across 4 pillars), broadcast
// via __shfl (no 2nd memory trip), issue up to 16 independent x-row loads in
// 2 batches of 8. Tail loop only for count>16 (~0.2% of pillars).
// hist/scan/scatter unchanged from R7 (283.6us) for attribution.
//
// ws layout: [counts: NB i32][gtotal+pad: 64 i32][base: NB i32]
//            [rank: NP i32][sorted: NP i32]   total ~18.1 MB

#define NP   2000000
#define NB   262144          // 512*512 pillars

__global__ __launch_bounds__(256) void zero_kernel(int4* __restrict__ p, int n4)
{
    const int stride = gridDim.x * blockDim.x;
    for (int i = blockIdx.x * blockDim.x + threadIdx.x; i < n4; i += stride)
        p[i] = make_int4(0, 0, 0, 0);
}

// Histogram; atomicAdd's old value = rank of point within its bin.
__global__ __launch_bounds__(256) void hist_rank_kernel(
    const int4* __restrict__ idx4, int* __restrict__ counts,
    int4* __restrict__ rank4)
{
    const int stride = gridDim.x * blockDim.x;
    for (int i = blockIdx.x * blockDim.x + threadIdx.x; i < NP / 4; i += stride) {
        const int4 v = idx4[i];
        int4 r;
        r.x = atomicAdd(&counts[v.x], 1);
        r.y = atomicAdd(&counts[v.y], 1);
        r.z = atomicAdd(&counts[v.z], 1);
        r.w = atomicAdd(&counts[v.w], 1);
        rank4[i] = r;
    }
}

// 256 blocks x 256 threads, 4 bins/thread. Block base via atomic ticket:
// any disjoint partition of [0,NP) is a valid CSR (order irrelevant).
__global__ __launch_bounds__(256) void scan_kernel(
    const int4* __restrict__ counts4, int* __restrict__ gtotal,
    int4* __restrict__ base4)
{
    __shared__ int lsum[256];
    __shared__ int blockBase;
    const int tid = threadIdx.x;
    const int g   = blockIdx.x * 256 + tid;

    const int4 c = counts4[g];
    const int s = c.x + c.y + c.z + c.w;
    lsum[tid] = s;
    __syncthreads();
    #pragma unroll
    for (int off = 1; off < 256; off <<= 1) {
        const int v = (tid >= off) ? lsum[tid - off] : 0;
        __syncthreads();
        lsum[tid] += v;
        __syncthreads();
    }
    const int incl = lsum[tid];
    if (tid == 255) blockBase = atomicAdd(gtotal, incl);
    __syncthreads();

    const int e = blockBase + (incl - s);
    base4[g] = make_int4(e, e + c.x, e + c.x + c.y, e + c.x + c.y + c.z);
}

// pos = base[bin] + rank  (no atomics on cursors). atomicExch write avoids
// L2 write-allocate / cross-XCD dirty-line bounce for the random 4B store.
__global__ __launch_bounds__(256) void scatter_kernel(
    const int4* __restrict__ idx4, const int4* __restrict__ rank4,
    const int* __restrict__ base, int* __restrict__ sorted)
{
    const int stride = gridDim.x * blockDim.x;
    for (int i = blockIdx.x * blockDim.x + threadIdx.x; i < NP / 4; i += stride) {
        const int4 v = idx4[i];
        const int4 r = rank4[i];
        const int p  = 4 * i;
        atomicExch(&sorted[base[v.x] + r.x], p + 0);
        atomicExch(&sorted[base[v.y] + r.y], p + 1);
        atomicExch(&sorted[base[v.z] + r.z], p + 2);
        atomicExch(&sorted[base[v.w] + r.w], p + 3);
    }
}

// One block per 64 consecutive pillars; 16 lanes per pillar (lane j owns
// channels 4j..4j+3). Segment ids prefetched lane-distributed and broadcast
// with __shfl; up to 16 independent 256B x-row loads in flight per pillar.
__global__ __launch_bounds__(256) void gather_kernel(
    const float4* __restrict__ x4,
    const int*    __restrict__ counts,
    const int*    __restrict__ base,
    const int*    __restrict__ sorted,
    float*        __restrict__ out)
{
    __shared__ float tile[64][65];
    const int tid = threadIdx.x;
    const int p0  = blockIdx.x * 64;
    const int j   = tid & 15;            // channel quad
    const int g   = tid >> 4;            // group id (16 groups)

    // Prefetch metadata + first 16 segment ids for all 4 pillars of this
    // group. Lane j holds id #j of each segment (one coalesced 64B load per
    // pillar; all 4 issued back-to-back -> sorted latency paid once).
    int beg_[4], cnt_[4], myid_[4];
    #pragma unroll
    for (int k = 0; k < 4; ++k) {
        const int p = p0 + g + 16 * k;
        beg_[k] = base[p];
        cnt_[k] = counts[p];
    }
    #pragma unroll
    for (int k = 0; k < 4; ++k)
        myid_[k] = (j < cnt_[k]) ? sorted[beg_[k] + j] : 0;

    #pragma unroll
    for (int k = 0; k < 4; ++k) {
        const int pl  = g + 16 * k;
        const int cnt = cnt_[k];
        const int beg = beg_[k];
        const int n   = (cnt < 16) ? cnt : 16;
        float4 a0 = make_float4(0.f, 0.f, 0.f, 0.f);
        float4 a1 = a0;

        // Batch 1: points 0..7 — 8 independent loads in flight.
        {
            float4 v[8];
            #pragma unroll
            for (int q = 0; q < 8; ++q) {
                const int id = __shfl(myid_[k], q, 16);
                if (q < n) v[q] = x4[(size_t)id * 16 + j];
            }
            #pragma unroll
            for (int q = 0; q < 8; ++q)
                if (q < n) {
                    a0.x += v[q].x; a0.y += v[q].y;
                    a0.z += v[q].z; a0.w += v[q].w;
                }
        }
        // Batch 2: points 8..15.
        if (n > 8) {
            float4 v[8];
            #pragma unroll
            for (int q = 8; q < 16; ++q) {
                const int id = __shfl(myid_[k], q, 16);
                if (q < n) v[q - 8] = x4[(size_t)id * 16 + j];
            }
            #pragma unroll
            for (int q = 8; q < 16; ++q)
                if (q < n) {
                    a1.x += v[q - 8].x; a1.y += v[q - 8].y;
                    a1.z += v[q - 8].z; a1.w += v[q - 8].w;
                }
        }
        // Rare tail: count > 16 (~0.2% of pillars at Poisson lambda=7.6).
        for (int t = beg + 16; t < beg + cnt; ++t) {
            const int id = sorted[t];
            const float4 vv = x4[(size_t)id * 16 + j];
            a0.x += vv.x; a0.y += vv.y; a0.z += vv.z; a0.w += vv.w;
        }

        tile[4 * j + 0][pl] = a0.x + a1.x;
        tile[4 * j + 1][pl] = a0.y + a1.y;
        tile[4 * j + 2][pl] = a0.z + a1.z;
        tile[4 * j + 3][pl] = a0.w + a1.w;
    }
    __syncthreads();

    const int pl = tid & 63;
    const int cb = tid >> 6;
    #pragma unroll
    for (int c4 = 0; c4 < 64; c4 += 4) {
        const int c = c4 + cb;
        __builtin_nontemporal_store(tile[c][pl], &out[(size_t)c * NB + p0 + pl]);
    }
}

// ---- Fallback (direct-atomic path) if workspace is too small ----
__global__ __launch_bounds__(256) void zero_out_kernel(float4* __restrict__ p, int n4)
{
    const int stride = gridDim.x * blockDim.x;
    for (int i = blockIdx.x * blockDim.x + threadIdx.x; i < n4; i += stride)
        p[i] = make_float4(0.f, 0.f, 0.f, 0.f);
}

__global__ __launch_bounds__(256) void pillar_scatter_fallback(
    const float* __restrict__ x, const int* __restrict__ idx,
    float* __restrict__ out)
{
    const int lane   = threadIdx.x & 15;
    const int group  = (blockIdx.x * blockDim.x + threadIdx.x) >> 4;
    const int stride = (gridDim.x * blockDim.x) >> 4;
    const float4* __restrict__ x4 = reinterpret_cast<const float4*>(x);
    for (int i = group; i < NP; i += stride) {
        const int p = idx[i];
        const float4 v = x4[i * 16 + lane];
        const int c = lane * 4;
        atomicAdd(&out[(size_t)(c + 0) * NB + p], v.x);
        atomicAdd(&out[(size_t)(c + 1) * NB + p], v.y);
        atomicAdd(&out[(size_t)(c + 2) * NB + p], v.z);
        atomicAdd(&out[(size_t)(c + 3) * NB + p], v.w);
    }
}

extern "C" void kernel_launch(void* const* d_in, const int* in_sizes, int n_in,
                              void* d_out, int out_size, void* d_ws, size_t ws_size,
                              hipStream_t stream)
{
    const float* x   = reinterpret_cast<const float*>(d_in[0]);
    const int*   idx = reinterpret_cast<const int*>(d_in[1]);
    float*       out = reinterpret_cast<float*>(d_out);

    const size_t needed = ((size_t)2 * NB + 64 + 2 * (size_t)NP) * sizeof(int);
    if (ws_size < needed) {
        zero_out_kernel<<<2048, 256, 0, stream>>>(
            reinterpret_cast<float4*>(out), out_size / 4);
        pillar_scatter_fallback<<<2048, 256, 0, stream>>>(x, idx, out);
        return;
    }

    int* counts = reinterpret_cast<int*>(d_ws);
    int* gtotal = counts + NB;
    int* base   = counts + NB + 64;
    int* rank   = base + NB;
    int* sorted = rank + NP;

    const int4* idx4 = reinterpret_cast<const int4*>(idx);

    zero_kernel<<<256, 256, 0, stream>>>(
        reinterpret_cast<int4*>(counts), (NB + 64) / 4);
    hist_rank_kernel<<<2048, 256, 0, stream>>>(
        idx4, counts, reinterpret_cast<int4*>(rank));
    scan_kernel<<<NB / 1024, 256, 0, stream>>>(
        reinterpret_cast<const int4*>(counts), gtotal,
        reinterpret_cast<int4*>(base));
    scatter_kernel<<<2048, 256, 0, stream>>>(
        idx4, reinterpret_cast<const int4*>(rank), base, sorted);
    gather_kernel<<<NB / 64, 256, 0, stream>>>(
        reinterpret_cast<const float4*>(x), counts, base, sorted, out);
}

// Round 10
// 281.654 us; speedup vs baseline: 1.0089x; 1.0089x over previous
//
#include <hip/hip_runtime.h>

// PillarFeatureNet scatter-sum:
//   out[c, p] = sum_{i : indices[i]==p} x[i, c]
// x: (2,000,000, 64) fp32, indices: (2,000,000) int32 in [0, 262144)
// out: (64, 262144) fp32
//
// Round 10 (= R9 with compile fix): __builtin_nontemporal_* requires native
// clang vector types, not HIP_vector_type structs -> use ext_vector_type
// typedefs + reinterpret_cast. Pipeline identical to R9's intent:
//  - pack (base,count) into int2 cursors (half the meta transactions),
//  - nontemporal loads on all single-use streams (idx, rank, sorted, x):
//    no L2 allocate -> hot counts/cursors lines survive,
//  - gather is R7's unroll-4 loop (R8 MLP variant measured identical).
//
// ws layout: [counts: NB i32][gtotal+pad: 64 i32][cursors: NB int2]
//            [rank: NP i32][sorted: NP i32]   total ~19.1 MB

#define NP   2000000
#define NB   262144          // 512*512 pillars

typedef int   nt_int4   __attribute__((ext_vector_type(4)));
typedef float nt_float4 __attribute__((ext_vector_type(4)));

__global__ __launch_bounds__(256) void zero_kernel(int4* __restrict__ p, int n4)
{
    const int stride = gridDim.x * blockDim.x;
    for (int i = blockIdx.x * blockDim.x + threadIdx.x; i < n4; i += stride)
        p[i] = make_int4(0, 0, 0, 0);
}

// Histogram; atomicAdd's old value = rank of point within its bin.
__global__ __launch_bounds__(256) void hist_rank_kernel(
    const int* __restrict__ idx, int* __restrict__ counts,
    int* __restrict__ rank)
{
    const nt_int4* idx4 = reinterpret_cast<const nt_int4*>(idx);
    nt_int4* rank4      = reinterpret_cast<nt_int4*>(rank);
    const int stride = gridDim.x * blockDim.x;
    for (int i = blockIdx.x * blockDim.x + threadIdx.x; i < NP / 4; i += stride) {
        const nt_int4 v = __builtin_nontemporal_load(&idx4[i]);
        nt_int4 r;
        r.x = atomicAdd(&counts[v.x], 1);
        r.y = atomicAdd(&counts[v.y], 1);
        r.z = atomicAdd(&counts[v.z], 1);
        r.w = atomicAdd(&counts[v.w], 1);
        __builtin_nontemporal_store(r, &rank4[i]);
    }
}

// 256 blocks x 256 threads, 4 bins/thread. Block base via atomic ticket:
// any disjoint partition of [0,NP) is a valid CSR (order irrelevant).
// Writes packed (base, count) int2 per bin.
__global__ __launch_bounds__(256) void scan_kernel(
    const int4* __restrict__ counts4, int* __restrict__ gtotal,
    int2* __restrict__ cursors)
{
    __shared__ int lsum[256];
    __shared__ int blockBase;
    const int tid = threadIdx.x;
    const int g   = blockIdx.x * 256 + tid;

    const int4 c = counts4[g];
    const int s = c.x + c.y + c.z + c.w;
    lsum[tid] = s;
    __syncthreads();
    #pragma unroll
    for (int off = 1; off < 256; off <<= 1) {
        const int v = (tid >= off) ? lsum[tid - off] : 0;
        __syncthreads();
        lsum[tid] += v;
        __syncthreads();
    }
    const int incl = lsum[tid];
    if (tid == 255) blockBase = atomicAdd(gtotal, incl);
    __syncthreads();

    const int e = blockBase + (incl - s);
    cursors[4 * g + 0] = make_int2(e, c.x);
    cursors[4 * g + 1] = make_int2(e + c.x, c.y);
    cursors[4 * g + 2] = make_int2(e + c.x + c.y, c.z);
    cursors[4 * g + 3] = make_int2(e + c.x + c.y + c.z, c.w);
}

// pos = base[bin] + rank  (no atomics on cursors). atomicExch write avoids
// L2 write-allocate / cross-XCD dirty-line bounce for the random 4B store.
__global__ __launch_bounds__(256) void scatter_kernel(
    const int* __restrict__ idx, const int* __restrict__ rank,
    const int2* __restrict__ cursors, int* __restrict__ sorted)
{
    const nt_int4* idx4  = reinterpret_cast<const nt_int4*>(idx);
    const nt_int4* rank4 = reinterpret_cast<const nt_int4*>(rank);
    const int stride = gridDim.x * blockDim.x;
    for (int i = blockIdx.x * blockDim.x + threadIdx.x; i < NP / 4; i += stride) {
        const nt_int4 v = __builtin_nontemporal_load(&idx4[i]);
        const nt_int4 r = __builtin_nontemporal_load(&rank4[i]);
        const int p  = 4 * i;
        atomicExch(&sorted[cursors[v.x].x + r.x], p + 0);
        atomicExch(&sorted[cursors[v.y].x + r.y], p + 1);
        atomicExch(&sorted[cursors[v.z].x + r.z], p + 2);
        atomicExch(&sorted[cursors[v.w].x + r.w], p + 3);
    }
}

// One block per 64 consecutive pillars. 16 lanes per pillar (lane j owns
// channels 4j..4j+3, float4 row gathers = 256B bursts). Unroll-4 keeps 4
// independent sorted->x chains in flight. Single-use streams (sorted, x)
// via nontemporal loads. Transpose via padded LDS tile, nontemporal
// coalesced output stores.
__global__ __launch_bounds__(256) void gather_kernel(
    const float* __restrict__ x,
    const int2*  __restrict__ cursors,
    const int*   __restrict__ sorted,
    float*       __restrict__ out)
{
    __shared__ float tile[64][65];
    const nt_float4* x4 = reinterpret_cast<const nt_float4*>(x);
    const int p0 = blockIdx.x * 64;
    const int j  = threadIdx.x & 15;
    const int g  = threadIdx.x >> 4;

    #pragma unroll
    for (int k = 0; k < 4; ++k) {
        const int pl  = g + 16 * k;
        const int2 bc = cursors[p0 + pl];
        const int beg = bc.x;
        const int end = bc.x + bc.y;
        nt_float4 a0 = {0.f, 0.f, 0.f, 0.f};
        nt_float4 a1 = a0, a2 = a0, a3 = a0;
        int t = beg;
        for (; t + 3 < end; t += 4) {
            const int i0 = __builtin_nontemporal_load(&sorted[t + 0]);
            const int i1 = __builtin_nontemporal_load(&sorted[t + 1]);
            const int i2 = __builtin_nontemporal_load(&sorted[t + 2]);
            const int i3 = __builtin_nontemporal_load(&sorted[t + 3]);
            const nt_float4 v0 = __builtin_nontemporal_load(&x4[(size_t)i0 * 16 + j]);
            const nt_float4 v1 = __builtin_nontemporal_load(&x4[(size_t)i1 * 16 + j]);
            const nt_float4 v2 = __builtin_nontemporal_load(&x4[(size_t)i2 * 16 + j]);
            const nt_float4 v3 = __builtin_nontemporal_load(&x4[(size_t)i3 * 16 + j]);
            a0 += v0; a1 += v1; a2 += v2; a3 += v3;
        }
        for (; t < end; ++t) {
            const int i0 = __builtin_nontemporal_load(&sorted[t]);
            const nt_float4 v0 = __builtin_nontemporal_load(&x4[(size_t)i0 * 16 + j]);
            a0 += v0;
        }
        const nt_float4 a = (a0 + a1) + (a2 + a3);
        tile[4 * j + 0][pl] = a.x;
        tile[4 * j + 1][pl] = a.y;
        tile[4 * j + 2][pl] = a.z;
        tile[4 * j + 3][pl] = a.w;
    }
    __syncthreads();

    const int pl = threadIdx.x & 63;
    const int cb = threadIdx.x >> 6;
    #pragma unroll
    for (int c4 = 0; c4 < 64; c4 += 4) {
        const int c = c4 + cb;
        __builtin_nontemporal_store(tile[c][pl], &out[(size_t)c * NB + p0 + pl]);
    }
}

// ---- Fallback (direct-atomic path) if workspace is too small ----
__global__ __launch_bounds__(256) void zero_out_kernel(float4* __restrict__ p, int n4)
{
    const int stride = gridDim.x * blockDim.x;
    for (int i = blockIdx.x * blockDim.x + threadIdx.x; i < n4; i += stride)
        p[i] = make_float4(0.f, 0.f, 0.f, 0.f);
}

__global__ __launch_bounds__(256) void pillar_scatter_fallback(
    const float* __restrict__ x, const int* __restrict__ idx,
    float* __restrict__ out)
{
    const int lane   = threadIdx.x & 15;
    const int group  = (blockIdx.x * blockDim.x + threadIdx.x) >> 4;
    const int stride = (gridDim.x * blockDim.x) >> 4;
    const float4* __restrict__ x4 = reinterpret_cast<const float4*>(x);
    for (int i = group; i < NP; i += stride) {
        const int p = idx[i];
        const float4 v = x4[i * 16 + lane];
        const int c = lane * 4;
        atomicAdd(&out[(size_t)(c + 0) * NB + p], v.x);
        atomicAdd(&out[(size_t)(c + 1) * NB + p], v.y);
        atomicAdd(&out[(size_t)(c + 2) * NB + p], v.z);
        atomicAdd(&out[(size_t)(c + 3) * NB + p], v.w);
    }
}

extern "C" void kernel_launch(void* const* d_in, const int* in_sizes, int n_in,
                              void* d_out, int out_size, void* d_ws, size_t ws_size,
                              hipStream_t stream)
{
    const float* x   = reinterpret_cast<const float*>(d_in[0]);
    const int*   idx = reinterpret_cast<const int*>(d_in[1]);
    float*       out = reinterpret_cast<float*>(d_out);

    const size_t needed = ((size_t)NB + 64 + 2 * (size_t)NB /*int2*/ +
                           2 * (size_t)NP) * sizeof(int);
    if (ws_size < needed) {
        zero_out_kernel<<<2048, 256, 0, stream>>>(
            reinterpret_cast<float4*>(out), out_size / 4);
        pillar_scatter_fallback<<<2048, 256, 0, stream>>>(x, idx, out);
        return;
    }

    int*  counts  = reinterpret_cast<int*>(d_ws);
    int*  gtotal  = counts + NB;
    int2* cursors = reinterpret_cast<int2*>(counts + NB + 64);
    int*  rank    = reinterpret_cast<int*>(cursors + NB);
    int*  sorted  = rank + NP;

    zero_kernel<<<256, 256, 0, stream>>>(
        reinterpret_cast<int4*>(counts), (NB + 64) / 4);
    hist_rank_kernel<<<2048, 256, 0, stream>>>(idx, counts, rank);
    scan_kernel<<<NB / 1024, 256, 0, stream>>>(
        reinterpret_cast<const int4*>(counts), gtotal, cursors);
    scatter_kernel<<<2048, 256, 0, stream>>>(idx, rank, cursors, sorted);
    gather_kernel<<<NB / 64, 256, 0, stream>>>(x, cursors, sorted, out);
}